// Round 12
// baseline (432.868 us; speedup 1.0000x reference)
//
#include <hip/hip_runtime.h>
#include <math.h>

// ---------------- sizes ----------------
#define DD 256
#define KK 512
#define LL 64
#define BB 8
#define SS 16
#define F_LOG2PI 1.83787706641f
#define PER_I 16777216u   // i-stride in per-half eps flat index (64*16*64*256)

typedef float v2f __attribute__((ext_vector_type(2)));

// ---------------- threefry2x32 (JAX-compatible) ----------------
struct U2 { unsigned x, y; };

__host__ __device__ constexpr U2 tf2x32(unsigned k0, unsigned k1, unsigned c0, unsigned c1) {
  unsigned ks2 = k0 ^ k1 ^ 0x1BD11BDAu;
  unsigned x0 = c0 + k0;
  unsigned x1 = c1 + k1;
#define TFR(r) { x0 += x1; x1 = (x1 << (r)) | (x1 >> (32 - (r))); x1 ^= x0; }
  TFR(13) TFR(15) TFR(26) TFR(6)   x0 += k1;  x1 += ks2 + 1u;
  TFR(17) TFR(29) TFR(16) TFR(24)  x0 += ks2; x1 += k0 + 2u;
  TFR(13) TFR(15) TFR(26) TFR(6)   x0 += k0;  x1 += k1 + 3u;
  TFR(17) TFR(29) TFR(16) TFR(24)  x0 += k1;  x1 += ks2 + 4u;
  TFR(13) TFR(15) TFR(26) TFR(6)   x0 += ks2; x1 += k0 + 5u;
#undef TFR
  return U2{x0, x1};
}

// Single-instruction rotate-left via v_alignbit_b32.
__device__ inline unsigned rotl(unsigned x, unsigned r) {
  return __builtin_amdgcn_alignbit(x, x, 32u - r);
}

// Threefry with c0=0 and k1 pre-folded into the counter (x1 = c1 + k1).
// Returns x0 ^ x1 (the JAX partitionable 32-bit draw).
__device__ inline unsigned tf_fold(unsigned k0, unsigned k1, unsigned x1) {
  unsigned ks2 = k0 ^ k1 ^ 0x1BD11BDAu;
  unsigned x0 = k0;
#define TFR(r) { x0 += x1; x1 = rotl(x1, r); x1 ^= x0; }
  TFR(13u) TFR(15u) TFR(26u) TFR(6u)   x0 += k1;  x1 += ks2 + 1u;
  TFR(17u) TFR(29u) TFR(16u) TFR(24u)  x0 += ks2; x1 += k0 + 2u;
  TFR(13u) TFR(15u) TFR(26u) TFR(6u)   x0 += k0;  x1 += k1 + 3u;
  TFR(17u) TFR(29u) TFR(16u) TFR(24u)  x0 += k1;  x1 += ks2 + 4u;
  TFR(13u) TFR(15u) TFR(26u) TFR(6u)   x0 += ks2; x1 += k0 + 5u;
#undef TFR
  return x0 ^ x1;
}

// Packed fma helper: <2 x float> fma -> v_pk_fma_f32 on gfx90a+.
__device__ inline v2f pkfma(v2f a, v2f b, v2f c) {
#if __has_builtin(__builtin_elementwise_fma)
  return __builtin_elementwise_fma(a, b, c);
#else
  v2f r; r.x = fmaf(a.x, b.x, c.x); r.y = fmaf(a.y, b.y, c.y); return r;
#endif
}

// bits -> p*u (eps = sqrt2*p*u; sqrt2 folded into caller's scale).
// Branchless; both erfinv polynomials as one packed chain, one final cndmask.
__device__ inline float normal_pu(unsigned b) {
  float two_fp = __uint_as_float((b >> 9) | 0x40000000u);     // 2*(1+frac) in [2,4)
  float u = fmaxf(-0.99999994f, two_fp - 3.0f);               // == 2f-1 exactly
  float w = -__logf(fmaf(-u, u, 1.0f));                       // -log(1-u*u)
  v2f ww; ww.x = w - 2.5f; ww.y = __builtin_amdgcn_sqrtf(w) - 3.0f;
  v2f p2; p2.x = 2.81022636e-08f; p2.y = -0.000200214257f;
  p2 = pkfma(p2, ww, (v2f){ 3.43273939e-07f,  0.000100950558f});
  p2 = pkfma(p2, ww, (v2f){-3.5233877e-06f,   0.00134934322f});
  p2 = pkfma(p2, ww, (v2f){-4.39150654e-06f, -0.00367342844f});
  p2 = pkfma(p2, ww, (v2f){ 0.00021858087f,   0.00573950773f});
  p2 = pkfma(p2, ww, (v2f){-0.00125372503f,  -0.0076224613f});
  p2 = pkfma(p2, ww, (v2f){-0.00417768164f,   0.00943887047f});
  p2 = pkfma(p2, ww, (v2f){ 0.246640727f,     1.00167406f});
  p2 = pkfma(p2, ww, (v2f){ 1.50140941f,      2.83297682f});
  float p = (w < 5.0f) ? p2.x : p2.y;
  return p * u;
}

// ---------------- kernels ----------------

// Fused: counting-sort (LDS-local) + prototype fusion + accbuf/lmacc/ctr
// zeroing. Block 0 publishes pos/lmap for k_tl.
__global__ void k_protos(const float* __restrict__ P, const float* __restrict__ he_p,
                         const int* __restrict__ labels, float4* __restrict__ pq,
                         float* __restrict__ cl, float4* __restrict__ accz,
                         float4* __restrict__ lmz, int* __restrict__ pos,
                         int* __restrict__ lmap, int* __restrict__ ctr) {
  int hb = blockIdx.x;             // h*64 + l
  int h = hb >> 6, l = hb & 63;
  int d = threadIdx.x;

  // zero accbuf (131072 float4: 4 per thread), lmacc (8192 float4), ctr (128)
  {
    float4 z; z.x = z.y = z.z = z.w = 0.0f;
    float4* base = accz + (hb * 256 + d) * 4;
#pragma unroll
    for (int j = 0; j < 4; ++j) base[j] = z;
    int gtid = hb * 256 + d;
    if (gtid < 8192) lmz[gtid] = z;
    if (d == 0) ctr[hb] = 0;
  }

  // ---- LDS counting-sort of balanced labels (robust to int64 labels) ----
  __shared__ int lab[512];
  __shared__ int cnt[64];
  __shared__ int mode;
  __shared__ int posl[512];
  if (d < 64) cnt[d] = 0;
  if (d == 0) mode = 0;
  __syncthreads();
  int v0 = labels[d], v1 = labels[d + 256];
  atomicAdd(&cnt[v0 & 63], 1);
  atomicAdd(&cnt[v1 & 63], 1);
  __syncthreads();
  if (d < 64 && cnt[d] != 8) mode = 1;   // benign same-value race
  __syncthreads();
  if (mode) { v0 = labels[2 * d]; v1 = labels[2 * (d + 256)]; }  // int64 LE low words
  lab[d] = v0 & 63; lab[d + 256] = v1 & 63;
  __syncthreads();
#pragma unroll
  for (int e = d; e < 512; e += 256) {
    int c = lab[e], o = 0;
    for (int j = 0; j < e; ++j) o += (lab[j] == c);
    posl[c * 8 + o] = e;               // idx of o-th occurrence of class c
  }
  __syncthreads();
  if (hb == 0) {                        // publish for k_tl
    pos[d] = posl[d]; pos[d + 256] = posl[d + 256];
    if (d < 64) lmap[d] = d;
  }

  // ---- prototype fusion ----
  float eps_var = expf(he_p[0]);
  int soff = h ? 0 : 4;            // support rows for this half
  float sinv = 0.f, sminv = 0.f;
#pragma unroll
  for (int j = 0; j < 4; ++j) {
    int row = posl[l * 8 + soff + j];
    float m = P[row * KK + d];
    float hh = P[row * KK + DD + d];
    float vv = eps_var + expf(hh);
    float iv = 1.0f / vv;
    sinv += iv; sminv += m * iv;
  }
  float nv = 1.0f / sinv;
  float nm = nv * sminv;
  float ev = eps_var + nv;         // exp(h_proto)
  float4 rec; rec.x = nm; rec.y = ev; rec.z = 1.0f / ev; rec.w = 0.0f;
  pq[(h * 256 + d) * 64 + l] = rec;
  float t = F_LOG2PI + __logf(ev);
  for (int off = 32; off; off >>= 1) t += __shfl_xor(t, off);
  __shared__ float red[4];
  int w = d >> 6, lane = d & 63;
  if (lane == 0) red[w] = t;
  __syncthreads();
  if (d == 0) cl[hb] = red[0] + red[1] + red[2] + red[3];
}

// Hot kernel (R8 core frozen) + last-block-done epilogue (replaces k_final).
// block=(h, lq, dchunk of 16); wave w = query i, lane = lp. 16 independent
// branchless threefry chains + fused lm partial. The 16th block to finish a
// given (h,lq) runs the epilogue for its 4 (g,lq) rows.
__global__ __launch_bounds__(256) void k_tl(const float* __restrict__ P,
    const int* __restrict__ pos, const float4* __restrict__ pq,
    float* __restrict__ accbuf, float* __restrict__ lmacc,
    const float* __restrict__ cl, const int* __restrict__ lmap,
    int* __restrict__ ctr, float* __restrict__ out) {
  constexpr U2 S1 = tf2x32(0u, 42u, 0u, 0u);  // foldlike split of key(42)
  constexpr U2 S2 = tf2x32(0u, 42u, 0u, 1u);
  int bb = blockIdx.x;             // h*1024 + lq*16 + chunk
  int h = bb >> 10;
  int lq = (bb >> 4) & 63;
  int chunk = bb & 15;
  int t = threadIdx.x;

  __shared__ float2 q[4 * 256];    // [i][d] = {m, exp(h)}
#pragma unroll
  for (int i = 0; i < 4; ++i) {
    int row = pos[lq * 8 + h * 4 + i];
    float2 rec;
    rec.x = P[row * KK + t];
    rec.y = expf(P[row * KK + DD + t]);
    q[i * 256 + t] = rec;
  }
  __syncthreads();

  int w = t >> 6, lane = t & 63;   // w = query i, lane = lp
  unsigned k0 = h ? S2.x : S1.x;
  unsigned k1 = h ? S2.y : S1.y;
  // eps flat idx (per half) = i*PER_I + lq*262144 + s*16384 + lp*256 + d
  // k1 folded into the counter base (threefry x1 init = c1 + k1).
  unsigned ebk = (unsigned)w * PER_I + (unsigned)lq * 262144u +
                 (unsigned)lane * 256u + (unsigned)chunk * 16u + k1;
  const float2* qd = &q[w * 256];
  const float4* pp = pq + (h * 256 + chunk * 16) * 64 + lane;
  int g = h * 4 + w;
  float* dst = accbuf + ((g * 64 + lq) * 16) * 64 + lane;

  float acc[16];
#pragma unroll
  for (int s = 0; s < 16; ++s) acc[s] = 0.0f;
  float lmpart = 0.0f;             // partial of sum_d(log vs + diff^2/vs)

#pragma unroll 1
  for (int dd = 0; dd < 16; ++dd) {
    float4 pr = pp[dd * 64];           // {mp, ev, ivp, -} coalesced, L2-hot
    float2 qv = qd[chunk * 16 + dd];   // broadcast ds_read_b64
    float vs  = qv.y + pr.y;
    float ivs = __builtin_amdgcn_rcpf(vs);
    float evs = pr.y * ivs;            // ev/vs
    float sivp = __builtin_amdgcn_sqrtf(pr.z);
    float dif = qv.x - pr.x;
    lmpart += __logf(vs) + dif * dif * ivs;              // lm term
    float A = dif * evs * sivp;                          // sign irrelevant (squared)
    float S = __builtin_amdgcn_sqrtf(qv.y * evs) * sivp * 1.41421356f; // sqrt2 folded
    unsigned ebkd = ebk + (unsigned)dd;
#pragma unroll
    for (int s = 0; s < 16; ++s) {
      unsigned bits = tf_fold(k0, k1, ebkd + (unsigned)s * 16384u);
      float eps = normal_pu(bits);
      float diff = fmaf(S, eps, A);
      acc[s] = fmaf(diff, diff, acc[s]);
    }
  }
#pragma unroll
  for (int s = 0; s < 16; ++s) atomicAdd(dst + s * 64, acc[s]);
  atomicAdd(lmacc + (g * 64 + lq) * 64 + lane, lmpart);

  // ---- last-block-done epilogue for this (h,lq) ----
  __threadfence();                 // release: all atomics visible before bump
  __shared__ int lastflag;
  if (t == 0) lastflag = (atomicAdd(&ctr[h * 64 + lq], 1) == 15);
  __syncthreads();
  if (!lastflag) return;
  __threadfence();                 // acquire

  // wave w handles row bb_w = (g=h*4+w, lq): 16 lse over lp, lse over s, scatter
  int rowbase = (g * 64 + lq);     // == bb_w
  volatile const float* acc_v = accbuf + rowbase * 16 * 64;
  volatile const float* lm_v  = lmacc + rowbase * 64;
  float clv = cl[h * 64 + lane];
  float m16 = -INFINITY, se16 = 0.0f;
#pragma unroll 1
  for (int s = 0; s < 16; ++s) {
    float tlv = -0.5f * (clv + acc_v[s * 64 + lane]);
    float mx = tlv;
    for (int off = 32; off; off >>= 1) mx = fmaxf(mx, __shfl_xor(mx, off));
    float se = expf(tlv - mx);
    for (int off = 32; off; off >>= 1) se += __shfl_xor(se, off);
    float a = -(mx + __logf(se));  // -lse_s (uniform across lanes)
    float nm = fmaxf(m16, a);
    se16 = se16 * expf(m16 - nm) + expf(a - nm);
    m16 = nm;
  }
  float mc = m16 + __logf(se16) - 2.7725887f;   // - log(16)
  float lmv = -0.5f * (256.0f * F_LOG2PI + lm_v[lane]);
  int row = pos[lq * 8 + g];
  out[row * 64 + lmap[lane]] = lmv + mc;
}

// ---------------- launch ----------------
extern "C" void kernel_launch(void* const* d_in, const int* in_sizes, int n_in,
                              void* d_out, int out_size, void* d_ws, size_t ws_size,
                              hipStream_t stream) {
  (void)in_sizes; (void)n_in; (void)out_size; (void)ws_size;
  const float* P      = (const float*)d_in[0];   // (512, 512) f32
  const float* he     = (const float*)d_in[1];   // scalar
  const int*   labels = (const int*)d_in[2];     // (512,) int
  float* out = (float*)d_out;                    // (512, 64) f32

  float* ws = (float*)d_ws;
  float* accbuf = ws;                   // [8][64][16][64] = 524288 floats (2 MB)
  float* lmacc  = ws + 524288;          // [8][64][64] = 32768 floats
  float4* pq = (float4*)(ws + 557056);  // [2][256][64] float4 = 131072 floats
  float* cl  = ws + 688128;             // [2][64]
  int*   pos = (int*)(ws + 688256);     // [512]
  int*   lmp = pos + 512;               // [64]
  int*   ctr = lmp + 64;                // [128]

  hipLaunchKernelGGL(k_protos, dim3(128),  dim3(256), 0, stream, P, he, labels, pq, cl,
                     (float4*)accbuf, (float4*)lmacc, pos, lmp, ctr);
  hipLaunchKernelGGL(k_tl,     dim3(2048), dim3(256), 0, stream, P, pos, pq, accbuf,
                     lmacc, cl, lmp, ctr, out);
}

// Round 13
// 393.116 us; speedup vs baseline: 1.1011x; 1.1011x over previous
//
#include <hip/hip_runtime.h>
#include <math.h>

// ---------------- sizes ----------------
#define DD 256
#define KK 512
#define LL 64
#define BB 8
#define SS 16
#define F_LOG2PI 1.83787706641f
#define PER_I 16777216u   // i-stride in per-half eps flat index (64*16*64*256)

typedef float v2f __attribute__((ext_vector_type(2)));

// ---------------- threefry2x32 (JAX-compatible) ----------------
struct U2 { unsigned x, y; };

__host__ __device__ constexpr U2 tf2x32(unsigned k0, unsigned k1, unsigned c0, unsigned c1) {
  unsigned ks2 = k0 ^ k1 ^ 0x1BD11BDAu;
  unsigned x0 = c0 + k0;
  unsigned x1 = c1 + k1;
#define TFR(r) { x0 += x1; x1 = (x1 << (r)) | (x1 >> (32 - (r))); x1 ^= x0; }
  TFR(13) TFR(15) TFR(26) TFR(6)   x0 += k1;  x1 += ks2 + 1u;
  TFR(17) TFR(29) TFR(16) TFR(24)  x0 += ks2; x1 += k0 + 2u;
  TFR(13) TFR(15) TFR(26) TFR(6)   x0 += k0;  x1 += k1 + 3u;
  TFR(17) TFR(29) TFR(16) TFR(24)  x0 += k1;  x1 += ks2 + 4u;
  TFR(13) TFR(15) TFR(26) TFR(6)   x0 += ks2; x1 += k0 + 5u;
#undef TFR
  return U2{x0, x1};
}

// Single-instruction rotate-left via v_alignbit_b32.
__device__ inline unsigned rotl(unsigned x, unsigned r) {
  return __builtin_amdgcn_alignbit(x, x, 32u - r);
}

// Threefry with c0=0 and k1 pre-folded into the counter (x1 = c1 + k1).
// Returns x0 ^ x1 (the JAX partitionable 32-bit draw).
__device__ inline unsigned tf_fold(unsigned k0, unsigned k1, unsigned x1) {
  unsigned ks2 = k0 ^ k1 ^ 0x1BD11BDAu;
  unsigned x0 = k0;
#define TFR(r) { x0 += x1; x1 = rotl(x1, r); x1 ^= x0; }
  TFR(13u) TFR(15u) TFR(26u) TFR(6u)   x0 += k1;  x1 += ks2 + 1u;
  TFR(17u) TFR(29u) TFR(16u) TFR(24u)  x0 += ks2; x1 += k0 + 2u;
  TFR(13u) TFR(15u) TFR(26u) TFR(6u)   x0 += k0;  x1 += k1 + 3u;
  TFR(17u) TFR(29u) TFR(16u) TFR(24u)  x0 += k1;  x1 += ks2 + 4u;
  TFR(13u) TFR(15u) TFR(26u) TFR(6u)   x0 += ks2; x1 += k0 + 5u;
#undef TFR
  return x0 ^ x1;
}

// Packed fma helper: <2 x float> fma -> v_pk_fma_f32 on gfx90a+.
__device__ inline v2f pkfma(v2f a, v2f b, v2f c) {
#if __has_builtin(__builtin_elementwise_fma)
  return __builtin_elementwise_fma(a, b, c);
#else
  v2f r; r.x = fmaf(a.x, b.x, c.x); r.y = fmaf(a.y, b.y, c.y); return r;
#endif
}

// bits -> p*u (eps = sqrt2*p*u; sqrt2 folded into caller's scale).
// Branchless; both erfinv polynomials as one packed chain, one final cndmask.
__device__ inline float normal_pu(unsigned b) {
  float two_fp = __uint_as_float((b >> 9) | 0x40000000u);     // 2*(1+frac) in [2,4)
  float u = fmaxf(-0.99999994f, two_fp - 3.0f);               // == 2f-1 exactly
  float w = -__logf(fmaf(-u, u, 1.0f));                       // -log(1-u*u)
  v2f ww; ww.x = w - 2.5f; ww.y = __builtin_amdgcn_sqrtf(w) - 3.0f;
  v2f p2; p2.x = 2.81022636e-08f; p2.y = -0.000200214257f;
  p2 = pkfma(p2, ww, (v2f){ 3.43273939e-07f,  0.000100950558f});
  p2 = pkfma(p2, ww, (v2f){-3.5233877e-06f,   0.00134934322f});
  p2 = pkfma(p2, ww, (v2f){-4.39150654e-06f, -0.00367342844f});
  p2 = pkfma(p2, ww, (v2f){ 0.00021858087f,   0.00573950773f});
  p2 = pkfma(p2, ww, (v2f){-0.00125372503f,  -0.0076224613f});
  p2 = pkfma(p2, ww, (v2f){-0.00417768164f,   0.00943887047f});
  p2 = pkfma(p2, ww, (v2f){ 0.246640727f,     1.00167406f});
  p2 = pkfma(p2, ww, (v2f){ 1.50140941f,      2.83297682f});
  float p = (w < 5.0f) ? p2.x : p2.y;
  return p * u;
}

// ---------------- kernels ----------------

// Fused: counting-sort (recomputed per block, LDS-local) + prototype fusion
// + accbuf/lmacc zeroing. Block 0 publishes pos/lmap for k_tl/k_final.
__global__ void k_protos(const float* __restrict__ P, const float* __restrict__ he_p,
                         const int* __restrict__ labels, float4* __restrict__ pq,
                         float* __restrict__ cl, float4* __restrict__ accz,
                         float4* __restrict__ lmz, int* __restrict__ pos,
                         int* __restrict__ lmap) {
  int hb = blockIdx.x;             // h*64 + l
  int h = hb >> 6, l = hb & 63;
  int d = threadIdx.x;

  // zero accbuf (131072 float4 / 128 blocks / 256 thr = 4 each) and
  // lmacc (8192 float4: first 8192 global threads take one each)
  {
    float4 z; z.x = z.y = z.z = z.w = 0.0f;
    float4* base = accz + (hb * 256 + d) * 4;
#pragma unroll
    for (int j = 0; j < 4; ++j) base[j] = z;
    int gtid = hb * 256 + d;
    if (gtid < 8192) lmz[gtid] = z;
  }

  // ---- LDS counting-sort of balanced labels (robust to int64 labels) ----
  __shared__ int lab[512];
  __shared__ int cnt[64];
  __shared__ int mode;
  __shared__ int posl[512];
  if (d < 64) cnt[d] = 0;
  if (d == 0) mode = 0;
  __syncthreads();
  int v0 = labels[d], v1 = labels[d + 256];
  atomicAdd(&cnt[v0 & 63], 1);
  atomicAdd(&cnt[v1 & 63], 1);
  __syncthreads();
  if (d < 64 && cnt[d] != 8) mode = 1;   // benign same-value race
  __syncthreads();
  if (mode) { v0 = labels[2 * d]; v1 = labels[2 * (d + 256)]; }  // int64 LE low words
  lab[d] = v0 & 63; lab[d + 256] = v1 & 63;
  __syncthreads();
#pragma unroll
  for (int e = d; e < 512; e += 256) {
    int c = lab[e], o = 0;
    for (int j = 0; j < e; ++j) o += (lab[j] == c);
    posl[c * 8 + o] = e;               // idx of o-th occurrence of class c
  }
  __syncthreads();
  if (hb == 0) {                        // publish for k_tl / k_final
    pos[d] = posl[d]; pos[d + 256] = posl[d + 256];
    if (d < 64) lmap[d] = d;
  }

  // ---- prototype fusion ----
  float eps_var = expf(he_p[0]);
  int soff = h ? 0 : 4;            // support rows for this half
  float sinv = 0.f, sminv = 0.f;
#pragma unroll
  for (int j = 0; j < 4; ++j) {
    int row = posl[l * 8 + soff + j];
    float m = P[row * KK + d];
    float hh = P[row * KK + DD + d];
    float vv = eps_var + expf(hh);
    float iv = 1.0f / vv;
    sinv += iv; sminv += m * iv;
  }
  float nv = 1.0f / sinv;
  float nm = nv * sminv;
  float ev = eps_var + nv;         // exp(h_proto)
  float4 rec; rec.x = nm; rec.y = ev; rec.z = 1.0f / ev; rec.w = 0.0f;
  pq[(h * 256 + d) * 64 + l] = rec;
  float t = F_LOG2PI + __logf(ev);
  for (int off = 32; off; off >>= 1) t += __shfl_xor(t, off);
  __shared__ float red[4];
  int w = d >> 6, lane = d & 63;
  if (lane == 0) red[w] = t;
  __syncthreads();
  if (d == 0) cl[hb] = red[0] + red[1] + red[2] + red[3];
}

// Hot kernel (R8 core, frozen): block=(h, lq, dchunk of 16). wave w = query i,
// lane = lp. 16 independent branchless threefry chains. Also accumulates the
// lm (logmls) partial over its 16-d slice into lmacc (replaces k_lm).
__global__ __launch_bounds__(256) void k_tl(const float* __restrict__ P,
    const int* __restrict__ pos, const float4* __restrict__ pq,
    float* __restrict__ accbuf, float* __restrict__ lmacc) {
  constexpr U2 S1 = tf2x32(0u, 42u, 0u, 0u);  // foldlike split of key(42)
  constexpr U2 S2 = tf2x32(0u, 42u, 0u, 1u);
  int bb = blockIdx.x;             // h*1024 + lq*16 + chunk
  int h = bb >> 10;
  int lq = (bb >> 4) & 63;
  int chunk = bb & 15;
  int t = threadIdx.x;

  __shared__ float2 q[4 * 256];    // [i][d] = {m, exp(h)}
#pragma unroll
  for (int i = 0; i < 4; ++i) {
    int row = pos[lq * 8 + h * 4 + i];
    float2 rec;
    rec.x = P[row * KK + t];
    rec.y = expf(P[row * KK + DD + t]);
    q[i * 256 + t] = rec;
  }
  __syncthreads();

  int w = t >> 6, lane = t & 63;   // w = query i, lane = lp
  unsigned k0 = h ? S2.x : S1.x;
  unsigned k1 = h ? S2.y : S1.y;
  // eps flat idx (per half) = i*PER_I + lq*262144 + s*16384 + lp*256 + d
  // k1 folded into the counter base (threefry x1 init = c1 + k1).
  unsigned ebk = (unsigned)w * PER_I + (unsigned)lq * 262144u +
                 (unsigned)lane * 256u + (unsigned)chunk * 16u + k1;
  const float2* qd = &q[w * 256];
  const float4* pp = pq + (h * 256 + chunk * 16) * 64 + lane;
  int g = h * 4 + w;
  float* dst = accbuf + ((g * 64 + lq) * 16) * 64 + lane;

  float acc[16];
#pragma unroll
  for (int s = 0; s < 16; ++s) acc[s] = 0.0f;
  float lmpart = 0.0f;             // partial of sum_d(log vs + diff^2/vs)

#pragma unroll 1
  for (int dd = 0; dd < 16; ++dd) {
    float4 pr = pp[dd * 64];           // {mp, ev, ivp, -} coalesced, L2-hot
    float2 qv = qd[chunk * 16 + dd];   // broadcast ds_read_b64
    float vs  = qv.y + pr.y;
    float ivs = __builtin_amdgcn_rcpf(vs);
    float evs = pr.y * ivs;            // ev/vs
    float sivp = __builtin_amdgcn_sqrtf(pr.z);
    float dif = qv.x - pr.x;
    lmpart += __logf(vs) + dif * dif * ivs;              // lm term (was k_lm)
    float A = dif * evs * sivp;                          // sign irrelevant (squared)
    float S = __builtin_amdgcn_sqrtf(qv.y * evs) * sivp * 1.41421356f; // sqrt2 folded
    unsigned ebkd = ebk + (unsigned)dd;
#pragma unroll
    for (int s = 0; s < 16; ++s) {
      unsigned bits = tf_fold(k0, k1, ebkd + (unsigned)s * 16384u);
      float eps = normal_pu(bits);
      float diff = fmaf(S, eps, A);
      acc[s] = fmaf(diff, diff, acc[s]);
    }
  }
#pragma unroll
  for (int s = 0; s < 16; ++s) atomicAdd(dst + s * 64, acc[s]);
  atomicAdd(lmacc + (g * 64 + lq) * 64 + lane, lmpart);
}

// Merged epilogue: per (g,lq): 16 lse over lp (wave w does s=w*4..w*4+3),
// MC = logsumexp_s(-lse) - log S, lm = -0.5*(256*log2pi + lmacc), scatter.
__global__ void k_final(const float* __restrict__ lmacc, const float* __restrict__ accbuf,
                        const float* __restrict__ cl, const int* __restrict__ pos,
                        const int* __restrict__ lmap, float* __restrict__ out) {
  int bb = blockIdx.x;             // g*64 + lq
  int g = bb >> 6, lq = bb & 63;
  int h = g >> 2;
  int t = threadIdx.x, w = t >> 6, lane = t & 63;
  __shared__ float lsebuf[16];
  float clv = cl[h * 64 + lane];
#pragma unroll
  for (int j = 0; j < 4; ++j) {
    int s = w * 4 + j;
    float tlv = -0.5f * (clv + accbuf[(bb * 16 + s) * 64 + lane]);
    float mx = tlv;
    for (int off = 32; off; off >>= 1) mx = fmaxf(mx, __shfl_xor(mx, off));
    float se = expf(tlv - mx);
    for (int off = 32; off; off >>= 1) se += __shfl_xor(se, off);
    if (lane == 0) lsebuf[s] = mx + __logf(se);
  }
  __syncthreads();
  if (t < 64) {
    float a = (t < 16) ? -lsebuf[t] : -INFINITY;
    float mx = a;
    for (int off = 32; off; off >>= 1) mx = fmaxf(mx, __shfl_xor(mx, off));
    float e = (t < 16) ? expf(a - mx) : 0.0f;
    for (int off = 32; off; off >>= 1) e += __shfl_xor(e, off);
    float mc = mx + __logf(e) - 2.7725887f;   // - log(16)
    float lmv = -0.5f * (256.0f * F_LOG2PI + lmacc[bb * 64 + t]);
    int row = pos[lq * 8 + g];
    out[row * 64 + lmap[t]] = lmv + mc;
  }
}

// ---------------- launch ----------------
extern "C" void kernel_launch(void* const* d_in, const int* in_sizes, int n_in,
                              void* d_out, int out_size, void* d_ws, size_t ws_size,
                              hipStream_t stream) {
  (void)in_sizes; (void)n_in; (void)out_size; (void)ws_size;
  const float* P      = (const float*)d_in[0];   // (512, 512) f32
  const float* he     = (const float*)d_in[1];   // scalar
  const int*   labels = (const int*)d_in[2];     // (512,) int
  float* out = (float*)d_out;                    // (512, 64) f32

  float* ws = (float*)d_ws;
  float* accbuf = ws;                   // [8][64][16][64] = 524288 floats (2 MB)
  float* lmacc  = ws + 524288;          // [8][64][64] = 32768 floats
  float4* pq = (float4*)(ws + 557056);  // [2][256][64] float4 = 131072 floats
  float* cl  = ws + 688128;             // [2][64]
  int*   pos = (int*)(ws + 688256);     // [512]
  int*   lmp = pos + 512;               // [64]

  hipLaunchKernelGGL(k_protos, dim3(128),  dim3(256), 0, stream, P, he, labels, pq, cl,
                     (float4*)accbuf, (float4*)lmacc, pos, lmp);
  hipLaunchKernelGGL(k_tl,     dim3(2048), dim3(256), 0, stream, P, pos, pq, accbuf, lmacc);
  hipLaunchKernelGGL(k_final,  dim3(512),  dim3(256), 0, stream, lmacc, accbuf, cl, pos, lmp, out);
}